// Round 2
// baseline (1918.646 us; speedup 1.0000x reference)
//
#include <hip/hip_runtime.h>

// MixingBlock: per-token fused kernel. B=8 N=2048 CS=256 CV=128 K=3.
// Round 2: correctness baseline, f32 I/O (inputs/outputs are float32 per
// reference; round-1 NaN was f32-read-as-bf16). One block (256 thr) per token.

#define B_    8
#define N_    2048
#define CS_   256
#define CV_   128
#define KW_   3
#define FAN_S 1152   // K*(CS+CV)
#define FAN_V 1536   // K*(CS+2*CV)
#define EPS_  1e-6f

// sum across 256 threads (4 waves of 64)
__device__ __forceinline__ float block_sum256(float v, float* red) {
#pragma unroll
    for (int off = 32; off > 0; off >>= 1) v += __shfl_xor(v, off);
    if ((threadIdx.x & 63) == 0) red[threadIdx.x >> 6] = v;
    __syncthreads();
    const float s = red[0] + red[1] + red[2] + red[3];
    __syncthreads();   // protect red[] before next use
    return s;
}

__global__ __launch_bounds__(256) void mixing_block_kernel(
    const float* __restrict__ x_s,     // [B,N,CS]
    const float* __restrict__ x_v,     // [B,N,CV,3]
    const float* __restrict__ coords,  // [B,N,3]
    const float* __restrict__ Wcs,     // [FAN_S,CS]
    const float* __restrict__ Wcv,     // [FAN_V,CV]
    const float* __restrict__ Wss,     // [CS,CS]
    const float* __restrict__ Wsv,     // [CV,CV]
    float* __restrict__ out)           // z_s [B*N*CS] ++ z_v [B*N*CV*3]
{
    const int token = blockIdx.x;          // b*N + n
    const int n     = token & (N_ - 1);
    const int t     = threadIdx.x;
    const int tok0  = token - n;           // b*N
    const size_t ZV0 = (size_t)B_ * N_ * CS_;

    __shared__ float sc[FAN_S];
    __shared__ float vc[FAN_V][3];
    __shared__ float hs[CS_];
    __shared__ float hv[3][CV_];
    __shared__ float rh[KW_][3];
    __shared__ float red[4];

    // ---- rhat per window slot (edge-padded coords => rhat=0 at borders; k=1 => 0)
    if (t < KW_) {
        const int j  = n + t - 1;
        const int jc = j < 0 ? 0 : (j >= N_ ? N_ - 1 : j);
        const float* cj = coords + (size_t)(tok0 + jc) * 3;
        const float* c0 = coords + (size_t)token * 3;
        const float d0 = cj[0] - c0[0];
        const float d1 = cj[1] - c0[1];
        const float d2 = cj[2] - c0[2];
        const float dn = sqrtf(d0 * d0 + d1 * d1 + d2 * d2);
        const float inv = (dn > 1e-6f) ? (1.0f / dn) : 0.0f;
        rh[t][0] = d0 * inv; rh[t][1] = d1 * inv; rh[t][2] = d2 * inv;
    }
    __syncthreads();

    // ---- build scal_in: per k: [ s_win(256) | vdot(128) ]
    for (int p = t; p < FAN_S; p += 256) {
        const int k = p / (CS_ + CV_);
        const int c = p - k * (CS_ + CV_);
        const int j = n + k - 1;
        float val = 0.0f;
        if (j >= 0 && j < N_) {
            const size_t tj = (size_t)(tok0 + j);
            if (c < CS_) {
                val = x_s[tj * CS_ + c];
            } else {
                const float* vp = x_v + (tj * CV_ + (c - CS_)) * 3;
                val = vp[0] * rh[k][0] + vp[1] * rh[k][1] + vp[2] * rh[k][2];
            }
        }
        sc[p] = val;
    }
    // ---- build vec_in: per k: [ v_win(128) | s_rhat(256) | v_cross(128) ]
    for (int p = t; p < FAN_V; p += 256) {
        const int k = p >> 9;       // / 512
        const int c = p & 511;
        const int j = n + k - 1;
        float v0 = 0.0f, v1 = 0.0f, v2 = 0.0f;
        if (j >= 0 && j < N_) {
            const size_t tj = (size_t)(tok0 + j);
            if (c < CV_) {
                const float* vp = x_v + (tj * CV_ + c) * 3;
                v0 = vp[0]; v1 = vp[1]; v2 = vp[2];
            } else if (c < CV_ + CS_) {
                const float s = x_s[tj * CS_ + (c - CV_)];
                v0 = s * rh[k][0]; v1 = s * rh[k][1]; v2 = s * rh[k][2];
            } else {
                const float* vp = x_v + (tj * CV_ + (c - CV_ - CS_)) * 3;
                const float a0 = vp[0], a1 = vp[1], a2 = vp[2];
                v0 = a1 * rh[k][2] - a2 * rh[k][1];   // v x rhat
                v1 = a2 * rh[k][0] - a0 * rh[k][2];
                v2 = a0 * rh[k][1] - a1 * rh[k][0];
            }
        }
        vc[p][0] = v0; vc[p][1] = v1; vc[p][2] = v2;
    }
    __syncthreads();

    // ---- conv GEMVs (W L2-resident; LDS reads broadcast)
    const float inv_fs = 1.0f / sqrtf((float)FAN_S);
    const float inv_fv = 1.0f / sqrtf((float)FAN_V);

    float my_hs;
    {
        float acc = 0.0f;
        for (int p = 0; p < FAN_S; ++p)
            acc += sc[p] * Wcs[(size_t)p * CS_ + t];
        my_hs = acc * inv_fs;
    }
    // vector outputs: thread t -> (o = t&127, d = t>>7); threads t<128 also (o=t, d=2)
    const int o  = t & (CV_ - 1);
    const int dd = t >> 7;
    float hva, hvb = 0.0f;
    {
        float acc = 0.0f;
        for (int p = 0; p < FAN_V; ++p)
            acc += vc[p][dd] * Wcv[(size_t)p * CV_ + o];
        hva = acc * inv_fv;
    }
    if (t < CV_) {
        float acc = 0.0f;
        for (int p = 0; p < FAN_V; ++p)
            acc += vc[p][2] * Wcv[(size_t)p * CV_ + t];
        hvb = acc * inv_fv;
    }

    // ---- LN 1
    float mu  = block_sum256(my_hs, red) * (1.0f / CS_);
    float dif = my_hs - mu;
    float var = block_sum256(dif * dif, red) * (1.0f / CS_);
    float ssc = rsqrtf(var + EPS_);
    float pv  = hva * hva + ((t < CV_) ? hvb * hvb : 0.0f);
    float n2  = block_sum256(pv, red) * (1.0f / CV_);
    float vsc = rsqrtf(n2 + EPS_);
    my_hs = dif * ssc;
    hva *= vsc; hvb *= vsc;
    hs[t] = my_hs;
    hv[dd][o] = hva;
    if (t < CV_) hv[2][t] = hvb;
    __syncthreads();

    // ---- SelfInteraction (residual inside)
    float ys;
    {
        float acc = 0.0f;
        for (int c = 0; c < CS_; ++c)
            acc += hs[c] * Wss[(size_t)c * CS_ + t];
        ys = my_hs + acc * (1.0f / 16.0f);          // /sqrt(256)
    }
    const float inv_scv = 1.0f / sqrtf((float)CV_);
    float yva, yvb = 0.0f;
    {
        float acc = 0.0f;
        for (int c = 0; c < CV_; ++c)
            acc += hv[dd][c] * Wsv[(size_t)c * CV_ + o];
        yva = hva + acc * inv_scv;
    }
    if (t < CV_) {
        float acc = 0.0f;
        for (int c = 0; c < CV_; ++c)
            acc += hv[2][c] * Wsv[(size_t)c * CV_ + t];
        yvb = hvb + acc * inv_scv;
    }

    // ---- LN 2
    mu  = block_sum256(ys, red) * (1.0f / CS_);
    dif = ys - mu;
    var = block_sum256(dif * dif, red) * (1.0f / CS_);
    ssc = rsqrtf(var + EPS_);
    pv  = yva * yva + ((t < CV_) ? yvb * yvb : 0.0f);
    n2  = block_sum256(pv, red) * (1.0f / CV_);
    vsc = rsqrtf(n2 + EPS_);

    // ---- residual with block input
    float zs  = dif * ssc + x_s[(size_t)token * CS_ + t];
    float zva = yva * vsc + x_v[((size_t)token * CV_ + o) * 3 + dd];
    float zvb = (t < CV_) ? (yvb * vsc + x_v[((size_t)token * CV_ + t) * 3 + 2]) : 0.0f;

    // ---- LN 3 + store
    mu  = block_sum256(zs, red) * (1.0f / CS_);
    dif = zs - mu;
    var = block_sum256(dif * dif, red) * (1.0f / CS_);
    ssc = rsqrtf(var + EPS_);
    pv  = zva * zva + ((t < CV_) ? zvb * zvb : 0.0f);
    n2  = block_sum256(pv, red) * (1.0f / CV_);
    vsc = rsqrtf(n2 + EPS_);

    out[(size_t)token * CS_ + t] = dif * ssc;
    out[ZV0 + ((size_t)token * CV_ + o) * 3 + dd] = zva * vsc;
    if (t < CV_)
        out[ZV0 + ((size_t)token * CV_ + t) * 3 + 2] = zvb * vsc;
}

extern "C" void kernel_launch(void* const* d_in, const int* in_sizes, int n_in,
                              void* d_out, int out_size, void* d_ws, size_t ws_size,
                              hipStream_t stream) {
    const float* x_s    = (const float*)d_in[0];
    const float* x_v    = (const float*)d_in[1];
    const float* coords = (const float*)d_in[2];
    const float* Wcs    = (const float*)d_in[3];
    const float* Wcv    = (const float*)d_in[4];
    const float* Wss    = (const float*)d_in[5];
    const float* Wsv    = (const float*)d_in[6];
    float* out = (float*)d_out;

    dim3 grid(B_ * N_), block(256);
    hipLaunchKernelGGL(mixing_block_kernel, grid, block, 0, stream,
                       x_s, x_v, coords, Wcs, Wcv, Wss, Wsv, out);
}

// Round 3
// 261.557 us; speedup vs baseline: 7.3355x; 7.3355x over previous
//
#include <hip/hip_runtime.h>
#include <hip/hip_bf16.h>

// MixingBlock MFMA version. B=8 N=2048 CS=256 CV=128 K=3.
// Round 3: 32 tokens/block, 512 threads (8 waves). Conv + SI as bf16 MFMA
// GEMMs (16x16x32), features built on the fly in LDS, weights pre-transposed
// + bf16-converted into d_ws by a prep kernel. LN/residual in f32.

typedef __attribute__((ext_vector_type(8))) short short8;
typedef __attribute__((ext_vector_type(4))) float f32x4;
typedef unsigned short u16;

#define B_    8
#define N_    2048
#define CS_   256
#define CV_   128
#define EPS_  1e-6f

// ws layout (bf16 element offsets)
#define OFF_CS 0          // Wt_cs [256][1152]
#define OFF_CV 294912     // Wt_cv [128][1536]
#define OFF_SS 491520     // Wt_ss [256][256]
#define OFF_SV 557056     // Wt_sv [128][128]
// total 573440 elems = 1,146,880 bytes

#define MFMA(a, b, c) __builtin_amdgcn_mfma_f32_16x16x32_bf16((a), (b), (c), 0, 0, 0)

__device__ __forceinline__ u16 f2b(float v) {
    __hip_bfloat16 h = __float2bfloat16(v);
    return *reinterpret_cast<u16*>(&h);
}

__device__ __forceinline__ float wave_sum(float v) {
#pragma unroll
    for (int off = 32; off > 0; off >>= 1) v += __shfl_xor(v, off);
    return v;
}

// ---------------- weight prep: transpose + f32->bf16 into ws ----------------
__global__ __launch_bounds__(256) void prep_weights(
    const float* __restrict__ Wcs, const float* __restrict__ Wcv,
    const float* __restrict__ Wss, const float* __restrict__ Wsv,
    u16* __restrict__ ws)
{
    const int bid = blockIdx.x;
    const float* src; int K, N; u16* dst; int tile;
    if (bid < 288)      { src = Wcs; K = 1152; N = 256; dst = ws + OFF_CS; tile = bid; }
    else if (bid < 480) { src = Wcv; K = 1536; N = 128; dst = ws + OFF_CV; tile = bid - 288; }
    else if (bid < 544) { src = Wss; K = 256;  N = 256; dst = ws + OFF_SS; tile = bid - 480; }
    else                { src = Wsv; K = 128;  N = 128; dst = ws + OFF_SV; tile = bid - 544; }
    const int ntN = N >> 5;
    const int k0 = (tile / ntN) * 32, n0 = (tile % ntN) * 32;
    __shared__ float t[32][33];
    const int r = threadIdx.x >> 5, c = threadIdx.x & 31;
#pragma unroll
    for (int i = 0; i < 4; ++i)
        t[r + 8 * i][c] = src[(size_t)(k0 + r + 8 * i) * N + n0 + c];
    __syncthreads();
#pragma unroll
    for (int i = 0; i < 4; ++i)
        dst[(size_t)(n0 + r + 8 * i) * K + k0 + c] = f2b(t[c][r + 8 * i]);
}

// ---------------- LN helpers over LDS (per token, one wave per token) -------
__device__ __forceinline__ void ln_scal(float* hS, int w, int l) {
#pragma unroll 1
    for (int tt = w; tt < 32; tt += 8) {
        float v[4];
#pragma unroll
        for (int i = 0; i < 4; ++i) v[i] = hS[tt * 260 + l + 64 * i];
        float mu = wave_sum(v[0] + v[1] + v[2] + v[3]) * (1.0f / 256.0f);
        float q = 0.0f;
#pragma unroll
        for (int i = 0; i < 4; ++i) { float d = v[i] - mu; q += d * d; }
        q = wave_sum(q);
        float sc = rsqrtf(q * (1.0f / 256.0f) + EPS_);
#pragma unroll
        for (int i = 0; i < 4; ++i) hS[tt * 260 + l + 64 * i] = (v[i] - mu) * sc;
    }
}

__device__ __forceinline__ void ln_vec(float* hV, int w, int l) {
#pragma unroll 1
    for (int tt = w; tt < 32; tt += 8) {
        float vals[6]; float q = 0.0f; int c = 0;
#pragma unroll
        for (int d = 0; d < 3; ++d)
#pragma unroll
            for (int i = 0; i < 2; ++i) {
                float x = hV[d * 4224 + tt * 132 + l + 64 * i];
                vals[c++] = x; q += x * x;
            }
        q = wave_sum(q);
        float sc = rsqrtf(q * (1.0f / 128.0f) + EPS_);
        c = 0;
#pragma unroll
        for (int d = 0; d < 3; ++d)
#pragma unroll
            for (int i = 0; i < 2; ++i)
                hV[d * 4224 + tt * 132 + l + 64 * i] = vals[c++] * sc;
    }
}

// ---------------- main fused kernel ----------------
__global__ __launch_bounds__(512) void mixing_main(
    const float* __restrict__ x_s, const float* __restrict__ x_v,
    const float* __restrict__ coords, const u16* __restrict__ wt,
    float* __restrict__ out)
{
    __shared__ __align__(16) char smem[126976];
    __shared__ float rh[32][3][4];

    float* hS  = (float*)smem;              // [32][260] f32 (phase B+)
    float* hV  = (float*)(smem + 33280);    // [3][32][132] f32 (phase C+)
    u16*   fS  = (u16*)smem;                // [32][1160] bf16 (phase A/B alias)
    u16*   fV  = (u16*)(smem + 33280);      // [96][136] bf16 (phase C alias)
    u16*   hsb = (u16*)(smem + 83968);      // [32][264] bf16
    u16*   hvb = (u16*)(smem + 100864);     // [96][136] bf16

    const int tid = threadIdx.x;
    const int w = tid >> 6, l = tid & 63;
    const int lm = l & 15, lk8 = (l >> 4) * 8, lq4 = (l >> 4) * 4;
    const int gt0 = blockIdx.x * 32;
    const int n0 = gt0 & (N_ - 1);
    const int seq0 = gt0 - n0;
    const size_t ZV0 = (size_t)B_ * N_ * CS_;

    const u16* wt_cs = wt + OFF_CS;
    const u16* wt_cv = wt + OFF_CV;
    const u16* wt_ss = wt + OFF_SS;
    const u16* wt_sv = wt + OFF_SV;

    // ---- rhat[t][k][3]
    if (tid < 96) {
        const int t = tid / 3, k = tid - 3 * (tid / 3);
        const int jn = n0 + t + k - 1;
        const int jc = jn < 0 ? 0 : (jn > N_ - 1 ? N_ - 1 : jn);
        const float* cj = coords + (size_t)(seq0 + jc) * 3;
        const float* c0 = coords + (size_t)(gt0 + t) * 3;
        const float d0 = cj[0] - c0[0], d1 = cj[1] - c0[1], d2 = cj[2] - c0[2];
        const float dn = sqrtf(d0 * d0 + d1 * d1 + d2 * d2);
        const float inv = dn > 1e-6f ? 1.0f / dn : 0.0f;
        rh[t][k][0] = d0 * inv; rh[t][k][1] = d1 * inv; rh[t][k][2] = d2 * inv;
    }
    __syncthreads();

    // ---- build F_s [32 tok][1152] bf16: per k: [s_win(256) | vdot(128)]
#pragma unroll 4
    for (int i = 0; i < 72; ++i) {
        const int e = tid + i * 512;
        const int t = e / 1152, p = e - t * 1152;
        const int k = p / 384, c = p - k * 384;
        const int jn = n0 + t + k - 1;
        float val = 0.0f;
        if ((unsigned)jn < (unsigned)N_) {
            const size_t j = (size_t)(seq0 + jn);
            if (c < 256) val = x_s[j * 256 + c];
            else {
                const float* vp = &x_v[(j * 128 + (c - 256)) * 3];
                val = vp[0] * rh[t][k][0] + vp[1] * rh[t][k][1] + vp[2] * rh[t][k][2];
            }
        }
        fS[t * 1160 + p] = f2b(val);
    }
    __syncthreads();

    // ---- scalar conv GEMM: [32 x 1152] x [1152 x 256]
    const f32x4 fz = {0.f, 0.f, 0.f, 0.f};
    f32x4 acc[2][2] = {{fz, fz}, {fz, fz}};   // [m-frag][n-sub], nf = 2w+u
    for (int ks = 0; ks < 36; ++ks) {
        const int koff = ks * 32 + lk8;
        const short8 a0 = *reinterpret_cast<const short8*>(fS + (0 + lm) * 1160 + koff);
        const short8 a1 = *reinterpret_cast<const short8*>(fS + (16 + lm) * 1160 + koff);
#pragma unroll
        for (int u = 0; u < 2; ++u) {
            const int n = (2 * w + u) * 16 + lm;
            const short8 b = *reinterpret_cast<const short8*>(wt_cs + (size_t)n * 1152 + koff);
            acc[0][u] = MFMA(a0, b, acc[0][u]);
            acc[1][u] = MFMA(a1, b, acc[1][u]);
        }
    }
    __syncthreads();   // all F_s reads done before h_s aliases the region
    const float inv_fs = 0.029462783f;   // 1/sqrt(1152)
#pragma unroll
    for (int mi = 0; mi < 2; ++mi)
#pragma unroll
        for (int u = 0; u < 2; ++u)
#pragma unroll
            for (int q = 0; q < 4; ++q)
                hS[(mi * 16 + lq4 + q) * 260 + (2 * w + u) * 16 + lm] = acc[mi][u][q] * inv_fs;
    __syncthreads();
    ln_scal(hS, w, l);
    __syncthreads();

    // ---- vector conv GEMM: [96 x 1536] x [1536 x 128], K-tiled 12 x 128
    f32x4 accv[6] = {fz, fz, fz, fz, fz, fz};   // m-frags rows d*32+t; nf = w
    for (int kt = 0; kt < 12; ++kt) {
        const int k = kt >> 2, sub = kt & 3;
#pragma unroll 8
        for (int i = 0; i < 24; ++i) {
            const int e = tid + i * 512;
            const int row = e >> 7, kl = e & 127;
            const int d = row >> 5, t = row & 31;
            const int jn = n0 + t + k - 1;
            float val = 0.0f;
            if ((unsigned)jn < (unsigned)N_) {
                const size_t j = (size_t)(seq0 + jn);
                if (sub == 0) {
                    val = x_v[(j * 128 + kl) * 3 + d];
                } else if (sub == 3) {
                    const float* vp = &x_v[(j * 128 + kl) * 3];
                    const int d1 = d == 2 ? 0 : d + 1;
                    const int d2 = d == 0 ? 2 : d - 1;
                    val = vp[d1] * rh[t][k][d2] - vp[d2] * rh[t][k][d1];
                } else {
                    const int scch = (sub == 1) ? kl : 128 + kl;
                    val = x_s[j * 256 + scch] * rh[t][k][d];
                }
            }
            fV[row * 136 + kl] = f2b(val);
        }
        __syncthreads();
#pragma unroll
        for (int ks = 0; ks < 4; ++ks) {
            const int koff = ks * 32 + lk8;
            const short8 b = *reinterpret_cast<const short8*>(
                wt_cv + (size_t)(w * 16 + lm) * 1536 + kt * 128 + koff);
#pragma unroll
            for (int mi = 0; mi < 6; ++mi) {
                const short8 a = *reinterpret_cast<const short8*>(fV + (mi * 16 + lm) * 136 + koff);
                accv[mi] = MFMA(a, b, accv[mi]);
            }
        }
        __syncthreads();   // protect tile before next build / h_v alias
    }
    const float inv_fv = 0.025515519f;   // 1/sqrt(1536)
#pragma unroll
    for (int mi = 0; mi < 6; ++mi)
#pragma unroll
        for (int q = 0; q < 4; ++q) {
            const int row = mi * 16 + lq4 + q;
            hV[(row >> 5) * 4224 + (row & 31) * 132 + w * 16 + lm] = accv[mi][q] * inv_fv;
        }
    __syncthreads();
    ln_vec(hV, w, l);
    __syncthreads();

    // ---- bf16 copies of normalized h for SI GEMMs
#pragma unroll 4
    for (int i = 0; i < 16; ++i) {
        const int e = tid + i * 512;
        hsb[(e >> 8) * 264 + (e & 255)] = f2b(hS[(e >> 8) * 260 + (e & 255)]);
    }
#pragma unroll 4
    for (int i = 0; i < 24; ++i) {
        const int e = tid + i * 512;
        const int row = e >> 7, o = e & 127;
        hvb[row * 136 + o] = f2b(hV[(row >> 5) * 4224 + (row & 31) * 132 + o]);
    }
    __syncthreads();

    // ---- SI scalar: y_s = h_s + (h_s @ Wss)/16
    f32x4 accs[2][2] = {{fz, fz}, {fz, fz}};
#pragma unroll
    for (int ks = 0; ks < 8; ++ks) {
        const int koff = ks * 32 + lk8;
        const short8 a0 = *reinterpret_cast<const short8*>(hsb + (0 + lm) * 264 + koff);
        const short8 a1 = *reinterpret_cast<const short8*>(hsb + (16 + lm) * 264 + koff);
#pragma unroll
        for (int u = 0; u < 2; ++u) {
            const int n = (2 * w + u) * 16 + lm;
            const short8 b = *reinterpret_cast<const short8*>(wt_ss + (size_t)n * 256 + koff);
            accs[0][u] = MFMA(a0, b, accs[0][u]);
            accs[1][u] = MFMA(a1, b, accs[1][u]);
        }
    }
#pragma unroll
    for (int mi = 0; mi < 2; ++mi)
#pragma unroll
        for (int u = 0; u < 2; ++u)
#pragma unroll
            for (int q = 0; q < 4; ++q) {
                const int idx = (mi * 16 + lq4 + q) * 260 + (2 * w + u) * 16 + lm;
                hS[idx] = hS[idx] + accs[mi][u][q] * 0.0625f;
            }

    // ---- SI vector: y_v = h_v + (h_v @ Wsv)/sqrt(128)
    f32x4 accw[6] = {fz, fz, fz, fz, fz, fz};
#pragma unroll
    for (int ks = 0; ks < 4; ++ks) {
        const int koff = ks * 32 + lk8;
        const short8 b = *reinterpret_cast<const short8*>(wt_sv + (size_t)(w * 16 + lm) * 128 + koff);
#pragma unroll
        for (int mi = 0; mi < 6; ++mi) {
            const short8 a = *reinterpret_cast<const short8*>(hvb + (mi * 16 + lm) * 136 + koff);
            accw[mi] = MFMA(a, b, accw[mi]);
        }
    }
#pragma unroll
    for (int mi = 0; mi < 6; ++mi)
#pragma unroll
        for (int q = 0; q < 4; ++q) {
            const int row = mi * 16 + lq4 + q;
            const int idx = (row >> 5) * 4224 + (row & 31) * 132 + w * 16 + lm;
            hV[idx] = hV[idx] + accw[mi][q] * 0.08838834765f;
        }
    __syncthreads();

    // ---- LN2
    ln_scal(hS, w, l);
    ln_vec(hV, w, l);
    __syncthreads();

    // ---- residual with block input
#pragma unroll 4
    for (int i = 0; i < 16; ++i) {
        const int e = tid + i * 512;
        hS[(e >> 8) * 260 + (e & 255)] += x_s[(size_t)gt0 * 256 + e];
    }
#pragma unroll 4
    for (int i = 0; i < 24; ++i) {
        const int e = tid + i * 512;
        const int t = e / 384, r = e - t * 384;
        const int o = r / 3, d = r - o * 3;
        hV[d * 4224 + t * 132 + o] += x_v[(size_t)gt0 * 384 + e];
    }
    __syncthreads();

    // ---- LN3 + store
    ln_scal(hS, w, l);
    ln_vec(hV, w, l);
    __syncthreads();

#pragma unroll 4
    for (int i = 0; i < 16; ++i) {
        const int e = tid + i * 512;
        out[(size_t)gt0 * 256 + e] = hS[(e >> 8) * 260 + (e & 255)];
    }
#pragma unroll 4
    for (int i = 0; i < 24; ++i) {
        const int e = tid + i * 512;
        const int t = e / 384, r = e - t * 384;
        const int o = r / 3, d = r - o * 3;
        out[ZV0 + (size_t)gt0 * 384 + e] = hV[d * 4224 + t * 132 + o];
    }
}

extern "C" void kernel_launch(void* const* d_in, const int* in_sizes, int n_in,
                              void* d_out, int out_size, void* d_ws, size_t ws_size,
                              hipStream_t stream) {
    const float* x_s    = (const float*)d_in[0];
    const float* x_v    = (const float*)d_in[1];
    const float* coords = (const float*)d_in[2];
    const float* Wcs    = (const float*)d_in[3];
    const float* Wcv    = (const float*)d_in[4];
    const float* Wss    = (const float*)d_in[5];
    const float* Wsv    = (const float*)d_in[6];
    float* out = (float*)d_out;
    u16* ws = (u16*)d_ws;

    hipLaunchKernelGGL(prep_weights, dim3(560), dim3(256), 0, stream,
                       Wcs, Wcv, Wss, Wsv, ws);
    hipLaunchKernelGGL(mixing_main, dim3((B_ * N_) / 32), dim3(512), 0, stream,
                       x_s, x_v, coords, ws, out);
}

// Round 4
// 155.388 us; speedup vs baseline: 12.3474x; 1.6832x over previous
//
#include <hip/hip_runtime.h>
#include <hip/hip_bf16.h>

// MixingBlock round 4: register-resident intermediates, 16 tok/block,
// 256 thr (4 waves), K-tiled feature build, s_rhat CG path factorized out
// of the vector conv GEMM. LDS 39.7KB -> 4 blocks/CU.

typedef __attribute__((ext_vector_type(8))) short short8;
typedef __attribute__((ext_vector_type(4))) short short4v;
typedef __attribute__((ext_vector_type(4))) float f32x4;
typedef unsigned short u16;

#define B_   8
#define N_   2048
#define EPS_ 1e-6f
#define TB   16

// ws element offsets (bf16)
#define OFF_CS 0        // wt_cs [256][1152]  (k*384 col blocks: [s_win|vdot])
#define OFF_V  294912   // wt_v  [128][768]   (k*256: [vwin(128)|cross(128)])
#define OFF_G  393216   // wt_g  [128][768]   (k*256: s_rhat weights)
#define OFF_SS 491520   // wt_ss [256][256]
#define OFF_SV 557056   // wt_sv [128][128]

#define MFMA(a,b,c) __builtin_amdgcn_mfma_f32_16x16x32_bf16((a),(b),(c),0,0,0)

__device__ __forceinline__ u16 f2b(float v){ __hip_bfloat16 h=__float2bfloat16(v); return *(u16*)&h; }

// ---------------- weight prep: transpose + remap + f32->bf16 ----------------
__global__ __launch_bounds__(256) void prep_weights(
    const float* __restrict__ Wcs, const float* __restrict__ Wcv,
    const float* __restrict__ Wss, const float* __restrict__ Wsv,
    u16* __restrict__ ws)
{
    const int bid = blockIdx.x;
    const float* src; int N, r0, ld, c0; u16* dst; int tile;
    if (bid < 288)      { src=Wcs; N=256; r0=0; dst=ws+OFF_CS; ld=1152; c0=0; tile=bid; }
    else if (bid < 336) { int k=(bid-288)/16; tile=(bid-288)%16;
                          src=Wcv; N=128; r0=k*512;     dst=ws+OFF_V; ld=768; c0=k*256; }
    else if (bid < 432) { int k=(bid-336)/32; tile=(bid-336)%32;
                          src=Wcv; N=128; r0=k*512+128; dst=ws+OFF_G; ld=768; c0=k*256; }
    else if (bid < 480) { int k=(bid-432)/16; tile=(bid-432)%16;
                          src=Wcv; N=128; r0=k*512+384; dst=ws+OFF_V; ld=768; c0=k*256+128; }
    else if (bid < 544) { tile=bid-480; src=Wss; N=256; r0=0; dst=ws+OFF_SS; ld=256; c0=0; }
    else                { tile=bid-544; src=Wsv; N=128; r0=0; dst=ws+OFF_SV; ld=128; c0=0; }
    const int ntN = N >> 5;
    const int kt = (tile/ntN)*32, nn = (tile%ntN)*32;
    __shared__ float t[32][33];
    const int r = threadIdx.x >> 5, c = threadIdx.x & 31;
#pragma unroll
    for (int i = 0; i < 4; ++i)
        t[r+8*i][c] = src[(size_t)(r0+kt+r+8*i)*N + nn+c];
    __syncthreads();
#pragma unroll
    for (int i = 0; i < 4; ++i)
        dst[(size_t)(nn+r+8*i)*ld + c0+kt+c] = f2b(t[c][r+8*i]);
}

// LN reduce: butterfly over lm + cross-wave via red. Begins with a sync so
// red[] from a previous call is safe to overwrite.
__device__ __forceinline__ void ln_reduce(
    float p1[4], float p2[4], float pv[4], f32x4* red,
    int lm, int lq4, int w, float mu[4], float ss[4], float vs[4])
{
    __syncthreads();
#pragma unroll
    for (int m = 1; m < 16; m <<= 1)
#pragma unroll
        for (int q = 0; q < 4; ++q) {
            p1[q] += __shfl_xor(p1[q], m);
            p2[q] += __shfl_xor(p2[q], m);
            pv[q] += __shfl_xor(pv[q], m);
        }
    if (lm == 0) {
#pragma unroll
        for (int q = 0; q < 4; ++q) {
            f32x4 r = {p1[q], p2[q], pv[q], 0.f};
            red[(lq4+q)*4 + w] = r;
        }
    }
    __syncthreads();
#pragma unroll
    for (int q = 0; q < 4; ++q) {
        const int t = lq4 + q;
        const f32x4 rs = red[t*4+0] + red[t*4+1] + red[t*4+2] + red[t*4+3];
        const float m_ = rs.x * (1.f/256.f);
        mu[q] = m_;
        ss[q] = rsqrtf(rs.y * (1.f/256.f) - m_*m_ + EPS_);
        vs[q] = rsqrtf(rs.z * (1.f/128.f) + EPS_);
    }
}

__global__ __launch_bounds__(256, 4) void mixing_main(
    const float* __restrict__ x_s, const float* __restrict__ x_v,
    const float* __restrict__ coords, const u16* __restrict__ wt,
    float* __restrict__ out)
{
    __shared__ __align__(16) char smem[39680];
    u16* fs  = (u16*)smem;                 // [16][392]: [s_win 256|vdot 128|pad]
    u16* fv  = (u16*)(smem + 12544);       // [48][264]: rows d*16+t: [vwin|cross|pad]
    u16* hsb = (u16*)smem;                 // [16][264] alias (post conv)
    u16* hvb = (u16*)(smem + 12544);       // [48][136] alias (post conv)
    float* rhp = (float*)(smem + 37888);   // [16][3][4]
    f32x4* red = (f32x4*)(smem + 38656);   // [16][4]

    const int tid = threadIdx.x;
    const int w   = tid >> 6, l = tid & 63;
    const int lm  = l & 15, lk8 = (l >> 4) << 3, lq4 = (l >> 4) << 2;
    const int gt0 = blockIdx.x * TB;
    const int n0  = gt0 & (N_ - 1);
    const int seq0 = gt0 - n0;
    const size_t ZV0 = (size_t)B_ * N_ * 256;

    // rhat
    if (tid < 48) {
        const int t = tid / 3, k = tid - 3 * (tid / 3);
        const int jn = n0 + t + k - 1;
        const int jc = jn < 0 ? 0 : (jn > N_-1 ? N_-1 : jn);
        const float* cj = coords + (size_t)(seq0 + jc) * 3;
        const float* c0p = coords + (size_t)(gt0 + t) * 3;
        const float d0 = cj[0]-c0p[0], d1 = cj[1]-c0p[1], d2 = cj[2]-c0p[2];
        const float dn = sqrtf(d0*d0 + d1*d1 + d2*d2);
        const float inv = dn > 1e-6f ? 1.f/dn : 0.f;
        rhp[(t*3+k)*4+0] = d0*inv; rhp[(t*3+k)*4+1] = d1*inv; rhp[(t*3+k)*4+2] = d2*inv;
    }
    __syncthreads();

    const f32x4 fz = {0.f,0.f,0.f,0.f};
    f32x4 acc_s[4] = {fz,fz,fz,fz};                       // scalar conv: u=0..3
    f32x4 acc_g[3][2] = {{fz,fz},{fz,fz},{fz,fz}};        // g per k: u=0..1
    f32x4 accv[3][2]  = {{fz,fz},{fz,fz},{fz,fz}};        // vec conv: mi=d, u=0..1

    const int bt = tid >> 4;       // token 0..15
    const int bx = tid & 15;

#pragma unroll
    for (int k = 0; k < 3; ++k) {
        const int jn = n0 + bt + k - 1;
        const bool valid = (unsigned)jn < (unsigned)N_;
        const size_t j = (size_t)seq0 + (valid ? jn : 0);
        // ---- s_win: 16 channels/thread
        {
            const int c0 = bx * 16;
            float v[16];
            if (valid) {
                const float4* sp = (const float4*)(x_s + j*256 + c0);
#pragma unroll
                for (int i = 0; i < 4; ++i) {
                    float4 f = sp[i];
                    v[4*i]=f.x; v[4*i+1]=f.y; v[4*i+2]=f.z; v[4*i+3]=f.w;
                }
            } else {
#pragma unroll
                for (int i = 0; i < 16; ++i) v[i] = 0.f;
            }
            short8 p0, p1;
#pragma unroll
            for (int i = 0; i < 8; ++i) { p0[i]=(short)f2b(v[i]); p1[i]=(short)f2b(v[8+i]); }
            *(short8*)(fs + bt*392 + c0)     = p0;
            *(short8*)(fs + bt*392 + c0 + 8) = p1;
        }
        // ---- x_v-derived: vdot / vwin / cross, 8 channels/thread in 2 halves
        {
            const int c0 = bx * 8;
            const float r0 = rhp[(bt*3+k)*4+0];
            const float r1 = rhp[(bt*3+k)*4+1];
            const float r2 = rhp[(bt*3+k)*4+2];
#pragma unroll
            for (int hh = 0; hh < 2; ++hh) {
                float vv[12];
                if (valid) {
                    const float4* vp = (const float4*)(x_v + ((size_t)j*128 + c0 + 4*hh)*3);
#pragma unroll
                    for (int i = 0; i < 3; ++i) {
                        float4 f = vp[i];
                        vv[4*i]=f.x; vv[4*i+1]=f.y; vv[4*i+2]=f.z; vv[4*i+3]=f.w;
                    }
                } else {
#pragma unroll
                    for (int i = 0; i < 12; ++i) vv[i] = 0.f;
                }
                short4v dv, w0, w1, w2, x0, x1, x2;
#pragma unroll
                for (int m = 0; m < 4; ++m) {
                    const float a0 = vv[3*m], a1 = vv[3*m+1], a2 = vv[3*m+2];
                    dv[m] = (short)f2b(a0*r0 + a1*r1 + a2*r2);
                    w0[m] = (short)f2b(a0); w1[m] = (short)f2b(a1); w2[m] = (short)f2b(a2);
                    x0[m] = (short)f2b(a1*r2 - a2*r1);
                    x1[m] = (short)f2b(a2*r0 - a0*r2);
                    x2[m] = (short)f2b(a0*r1 - a1*r0);
                }
                const int cc = c0 + 4*hh;
                *(short4v*)(fs + bt*392 + 256 + cc)      = dv;
                *(short4v*)(fv + (0*16+bt)*264 + cc)       = w0;
                *(short4v*)(fv + (1*16+bt)*264 + cc)       = w1;
                *(short4v*)(fv + (2*16+bt)*264 + cc)       = w2;
                *(short4v*)(fv + (0*16+bt)*264 + 128 + cc) = x0;
                *(short4v*)(fv + (1*16+bt)*264 + 128 + cc) = x1;
                *(short4v*)(fv + (2*16+bt)*264 + 128 + cc) = x2;
            }
        }
        __syncthreads();

        // ---- scalar conv GEMM: K slice k*384, 12 steps
        const u16* wcs_base = wt + OFF_CS + k*384;
#pragma unroll
        for (int ks = 0; ks < 12; ++ks) {
            const int koff = ks*32 + lk8;
            const short8 a = *(const short8*)(fs + lm*392 + koff);
#pragma unroll
            for (int u = 0; u < 4; ++u) {
                const short8 b = *(const short8*)(wcs_base + (size_t)((4*w+u)*16+lm)*1152 + koff);
                acc_s[u] = MFMA(a, b, acc_s[u]);
            }
        }
        // ---- g GEMM: A = s_win cols of fs, K=256
        const u16* wg_base = wt + OFF_G + k*256;
#pragma unroll
        for (int ks = 0; ks < 8; ++ks) {
            const int koff = ks*32 + lk8;
            const short8 a = *(const short8*)(fs + lm*392 + koff);
#pragma unroll
            for (int u = 0; u < 2; ++u) {
                const short8 b = *(const short8*)(wg_base + (size_t)((2*w+u)*16+lm)*768 + koff);
                acc_g[k][u] = MFMA(a, b, acc_g[k][u]);
            }
        }
        // ---- vec conv GEMM: [48 x 256] x [256 x 128]
        const u16* wv_base = wt + OFF_V + k*256;
#pragma unroll
        for (int ks = 0; ks < 8; ++ks) {
            const int koff = ks*32 + lk8;
#pragma unroll
            for (int u = 0; u < 2; ++u) {
                const short8 b = *(const short8*)(wv_base + (size_t)((2*w+u)*16+lm)*768 + koff);
#pragma unroll
                for (int mi = 0; mi < 3; ++mi) {
                    const short8 a = *(const short8*)(fv + (mi*16+lm)*264 + koff);
                    accv[mi][u] = MFMA(a, b, accv[mi][u]);
                }
            }
        }
        __syncthreads();
    }

    // ---- scales + g-combine (register-aligned: same (t,o) mapping)
    const float inv_fs = 0.029462783f;     // 1/sqrt(1152)
    const float inv_fv = 0.0255155136f;    // 1/sqrt(1536)
#pragma unroll
    for (int u = 0; u < 4; ++u)
#pragma unroll
        for (int q = 0; q < 4; ++q) acc_s[u][q] *= inv_fs;
#pragma unroll
    for (int mi = 0; mi < 3; ++mi)
#pragma unroll
        for (int u = 0; u < 2; ++u)
#pragma unroll
            for (int q = 0; q < 4; ++q) {
                const int t = lq4 + q;
                float s = accv[mi][u][q];
                s += acc_g[0][u][q] * rhp[(t*3+0)*4+mi];
                s += acc_g[1][u][q] * rhp[(t*3+1)*4+mi];
                s += acc_g[2][u][q] * rhp[(t*3+2)*4+mi];
                accv[mi][u][q] = s * inv_fv;
            }

    // ---- LN1
    float p1[4], p2[4], pv[4], mu[4], ss[4], vs[4];
#pragma unroll
    for (int q = 0; q < 4; ++q) {
        float a = 0.f, b = 0.f, c = 0.f;
#pragma unroll
        for (int u = 0; u < 4; ++u) { const float x = acc_s[u][q]; a += x; b += x*x; }
#pragma unroll
        for (int mi = 0; mi < 3; ++mi)
#pragma unroll
            for (int u = 0; u < 2; ++u) { const float x = accv[mi][u][q]; c += x*x; }
        p1[q] = a; p2[q] = b; pv[q] = c;
    }
    ln_reduce(p1, p2, pv, red, lm, lq4, w, mu, ss, vs);

    // apply + bf16 staging for SI (fs/fv regions safe: all conv reads done)
#pragma unroll
    for (int u = 0; u < 4; ++u)
#pragma unroll
        for (int q = 0; q < 4; ++q) {
            const float h = (acc_s[u][q] - mu[q]) * ss[q];
            acc_s[u][q] = h;
            hsb[(lq4+q)*264 + (4*w+u)*16 + lm] = f2b(h);
        }
#pragma unroll
    for (int mi = 0; mi < 3; ++mi)
#pragma unroll
        for (int u = 0; u < 2; ++u)
#pragma unroll
            for (int q = 0; q < 4; ++q) {
                const float h = accv[mi][u][q] * vs[q];
                accv[mi][u][q] = h;
                hvb[(mi*16+lq4+q)*136 + (2*w+u)*16 + lm] = f2b(h);
            }
    __syncthreads();

    // ---- SI GEMMs
    f32x4 accs[4] = {fz,fz,fz,fz};
    f32x4 accw[3][2] = {{fz,fz},{fz,fz},{fz,fz}};
    const u16* wss = wt + OFF_SS;
    const u16* wsv = wt + OFF_SV;
#pragma unroll
    for (int ks = 0; ks < 8; ++ks) {
        const int koff = ks*32 + lk8;
        const short8 a = *(const short8*)(hsb + lm*264 + koff);
#pragma unroll
        for (int u = 0; u < 4; ++u) {
            const short8 b = *(const short8*)(wss + (size_t)((4*w+u)*16+lm)*256 + koff);
            accs[u] = MFMA(a, b, accs[u]);
        }
    }
#pragma unroll
    for (int ks = 0; ks < 4; ++ks) {
        const int koff = ks*32 + lk8;
#pragma unroll
        for (int u = 0; u < 2; ++u) {
            const short8 b = *(const short8*)(wsv + (size_t)((2*w+u)*16+lm)*128 + koff);
#pragma unroll
            for (int mi = 0; mi < 3; ++mi) {
                const short8 a = *(const short8*)(hvb + (mi*16+lm)*136 + koff);
                accw[mi][u] = MFMA(a, b, accw[mi][u]);
            }
        }
    }

    // ---- y = h + SI (residual inside), then LN2
#pragma unroll
    for (int u = 0; u < 4; ++u)
#pragma unroll
        for (int q = 0; q < 4; ++q) acc_s[u][q] += accs[u][q] * 0.0625f;
#pragma unroll
    for (int mi = 0; mi < 3; ++mi)
#pragma unroll
        for (int u = 0; u < 2; ++u)
#pragma unroll
            for (int q = 0; q < 4; ++q) accv[mi][u][q] += accw[mi][u][q] * 0.08838834764f;

#pragma unroll
    for (int q = 0; q < 4; ++q) {
        float a = 0.f, b = 0.f, c = 0.f;
#pragma unroll
        for (int u = 0; u < 4; ++u) { const float x = acc_s[u][q]; a += x; b += x*x; }
#pragma unroll
        for (int mi = 0; mi < 3; ++mi)
#pragma unroll
            for (int u = 0; u < 2; ++u) { const float x = accv[mi][u][q]; c += x*x; }
        p1[q] = a; p2[q] = b; pv[q] = c;
    }
    ln_reduce(p1, p2, pv, red, lm, lq4, w, mu, ss, vs);

    // apply LN2 + block residual
#pragma unroll
    for (int u = 0; u < 4; ++u)
#pragma unroll
        for (int q = 0; q < 4; ++q) {
            acc_s[u][q] = (acc_s[u][q] - mu[q]) * ss[q]
                        + x_s[(size_t)(gt0 + lq4 + q)*256 + (4*w+u)*16 + lm];
        }
#pragma unroll
    for (int mi = 0; mi < 3; ++mi)
#pragma unroll
        for (int u = 0; u < 2; ++u)
#pragma unroll
            for (int q = 0; q < 4; ++q) {
                accv[mi][u][q] = accv[mi][u][q] * vs[q]
                    + x_v[((size_t)(gt0 + lq4 + q)*128 + (2*w+u)*16 + lm)*3 + mi];
            }

    // ---- LN3 + store
#pragma unroll
    for (int q = 0; q < 4; ++q) {
        float a = 0.f, b = 0.f, c = 0.f;
#pragma unroll
        for (int u = 0; u < 4; ++u) { const float x = acc_s[u][q]; a += x; b += x*x; }
#pragma unroll
        for (int mi = 0; mi < 3; ++mi)
#pragma unroll
            for (int u = 0; u < 2; ++u) { const float x = accv[mi][u][q]; c += x*x; }
        p1[q] = a; p2[q] = b; pv[q] = c;
    }
    ln_reduce(p1, p2, pv, red, lm, lq4, w, mu, ss, vs);

#pragma unroll
    for (int u = 0; u < 4; ++u)
#pragma unroll
        for (int q = 0; q < 4; ++q)
            out[(size_t)(gt0 + lq4 + q)*256 + (4*w+u)*16 + lm] = (acc_s[u][q] - mu[q]) * ss[q];
#pragma unroll
    for (int mi = 0; mi < 3; ++mi)
#pragma unroll
        for (int u = 0; u < 2; ++u)
#pragma unroll
            for (int q = 0; q < 4; ++q)
                out[ZV0 + ((size_t)(gt0 + lq4 + q)*128 + (2*w+u)*16 + lm)*3 + mi] = accv[mi][u][q] * vs[q];
}

extern "C" void kernel_launch(void* const* d_in, const int* in_sizes, int n_in,
                              void* d_out, int out_size, void* d_ws, size_t ws_size,
                              hipStream_t stream) {
    const float* x_s    = (const float*)d_in[0];
    const float* x_v    = (const float*)d_in[1];
    const float* coords = (const float*)d_in[2];
    const float* Wcs    = (const float*)d_in[3];
    const float* Wcv    = (const float*)d_in[4];
    const float* Wss    = (const float*)d_in[5];
    const float* Wsv    = (const float*)d_in[6];
    float* out = (float*)d_out;
    u16* ws = (u16*)d_ws;

    hipLaunchKernelGGL(prep_weights, dim3(560), dim3(256), 0, stream,
                       Wcs, Wcv, Wss, Wsv, ws);
    hipLaunchKernelGGL(mixing_main, dim3((B_ * N_) / TB), dim3(256), 0, stream,
                       x_s, x_v, coords, ws, out);
}

// Round 5
// 131.738 us; speedup vs baseline: 14.5641x; 1.1795x over previous
//
#include <hip/hip_runtime.h>
#include <hip/hip_bf16.h>

// MixingBlock round 5: 32 tok/block (512 thr, 8 waves), B-fragment register
// prefetch in all GEMM loops, per-k g-fold, LDS-staged x_v residual + z_v out.

typedef __attribute__((ext_vector_type(8))) short short8;
typedef __attribute__((ext_vector_type(4))) short short4v;
typedef __attribute__((ext_vector_type(4))) float f32x4;
typedef unsigned short u16;

#define B_   8
#define N_   2048
#define EPS_ 1e-6f
#define TB   32

// ws element offsets (bf16)
#define OFF_CS 0        // wt_cs [256][1152]  (k*384 col blocks: [s_win|vdot])
#define OFF_V  294912   // wt_v  [128][768]   (k*256: [vwin(128)|cross(128)])
#define OFF_G  393216   // wt_g  [128][768]   (k*256: s_rhat weights)
#define OFF_SS 491520   // wt_ss [256][256]
#define OFF_SV 557056   // wt_sv [128][128]

#define MFMA(a,b,c) __builtin_amdgcn_mfma_f32_16x16x32_bf16((a),(b),(c),0,0,0)

__device__ __forceinline__ u16 f2b(float v){ __hip_bfloat16 h=__float2bfloat16(v); return *(u16*)&h; }

// ---------------- weight prep: transpose + remap + f32->bf16 ----------------
__global__ __launch_bounds__(256) void prep_weights(
    const float* __restrict__ Wcs, const float* __restrict__ Wcv,
    const float* __restrict__ Wss, const float* __restrict__ Wsv,
    u16* __restrict__ ws)
{
    const int bid = blockIdx.x;
    const float* src; int N, r0, ld, c0; u16* dst; int tile;
    if (bid < 288)      { src=Wcs; N=256; r0=0; dst=ws+OFF_CS; ld=1152; c0=0; tile=bid; }
    else if (bid < 336) { int k=(bid-288)/16; tile=(bid-288)%16;
                          src=Wcv; N=128; r0=k*512;     dst=ws+OFF_V; ld=768; c0=k*256; }
    else if (bid < 432) { int k=(bid-336)/32; tile=(bid-336)%32;
                          src=Wcv; N=128; r0=k*512+128; dst=ws+OFF_G; ld=768; c0=k*256; }
    else if (bid < 480) { int k=(bid-432)/16; tile=(bid-432)%16;
                          src=Wcv; N=128; r0=k*512+384; dst=ws+OFF_V; ld=768; c0=k*256+128; }
    else if (bid < 544) { tile=bid-480; src=Wss; N=256; r0=0; dst=ws+OFF_SS; ld=256; c0=0; }
    else                { tile=bid-544; src=Wsv; N=128; r0=0; dst=ws+OFF_SV; ld=128; c0=0; }
    const int ntN = N >> 5;
    const int kt = (tile/ntN)*32, nn = (tile%ntN)*32;
    __shared__ float t[32][33];
    const int r = threadIdx.x >> 5, c = threadIdx.x & 31;
#pragma unroll
    for (int i = 0; i < 4; ++i)
        t[r+8*i][c] = src[(size_t)(r0+kt+r+8*i)*N + nn+c];
    __syncthreads();
#pragma unroll
    for (int i = 0; i < 4; ++i)
        dst[(size_t)(nn+r+8*i)*ld + c0+kt+c] = f2b(t[c][r+8*i]);
}

// LN reduce for 8 waves, 2 m-frags: butterfly over 16 lanes + cross-wave red.
__device__ __forceinline__ void ln_reduce8(
    float p1[2][4], float p2[2][4], float pv[2][4], f32x4* red,
    int lm, int lq4, int w, float mu[2][4], float ss[2][4], float vs[2][4])
{
    __syncthreads();
#pragma unroll
    for (int m2 = 1; m2 < 16; m2 <<= 1)
#pragma unroll
        for (int m = 0; m < 2; ++m)
#pragma unroll
            for (int q = 0; q < 4; ++q) {
                p1[m][q] += __shfl_xor(p1[m][q], m2);
                p2[m][q] += __shfl_xor(p2[m][q], m2);
                pv[m][q] += __shfl_xor(pv[m][q], m2);
            }
    if (lm == 0)
#pragma unroll
        for (int m = 0; m < 2; ++m)
#pragma unroll
            for (int q = 0; q < 4; ++q) {
                f32x4 r = {p1[m][q], p2[m][q], pv[m][q], 0.f};
                red[(m*16+lq4+q)*8 + w] = r;
            }
    __syncthreads();
#pragma unroll
    for (int m = 0; m < 2; ++m)
#pragma unroll
        for (int q = 0; q < 4; ++q) {
            const int t = m*16 + lq4 + q;
            f32x4 rs = red[t*8+0];
#pragma unroll
            for (int i = 1; i < 8; ++i) rs += red[t*8+i];
            const float mm = rs.x * (1.f/256.f);
            mu[m][q] = mm;
            ss[m][q] = rsqrtf(rs.y*(1.f/256.f) - mm*mm + EPS_);
            vs[m][q] = rsqrtf(rs.z*(1.f/128.f) + EPS_);
        }
}

__global__ __launch_bounds__(512, 4) void mixing_main(
    const float* __restrict__ x_s, const float* __restrict__ x_v,
    const float* __restrict__ coords, const u16* __restrict__ wt,
    float* __restrict__ out)
{
    __shared__ __align__(16) char smem[81408];
    u16* fs  = (u16*)smem;                  // [32][392]: [s_win 256|vdot 128|pad]
    u16* fv  = (u16*)(smem + 25088);        // [96][264]: rows d*32+t
    u16* hsb = (u16*)smem;                  // [32][264] alias
    u16* hvb = (u16*)(smem + 25088);        // [96][136] alias
    float* xvL = (float*)(smem + 25088);    // [32*384] f32 alias (post-SI)
    float* rhp = (float*)(smem + 75776);    // [32][3][4]
    f32x4* red = (f32x4*)(smem + 77312);    // [32][8]

    const int tid = threadIdx.x;
    const int w   = tid >> 6, l = tid & 63;
    const int lm  = l & 15, lk8 = (l >> 4) << 3, lq4 = (l >> 4) << 2;
    const int gt0 = blockIdx.x * TB;
    const int n0  = gt0 & (N_ - 1);
    const int seq0 = gt0 - n0;
    const size_t ZV0 = (size_t)B_ * N_ * 256;

    // rhat
    if (tid < 96) {
        const int t = tid / 3, k = tid - 3 * (tid / 3);
        const int jn = n0 + t + k - 1;
        const int jc = jn < 0 ? 0 : (jn > N_-1 ? N_-1 : jn);
        const float* cj = coords + (size_t)(seq0 + jc) * 3;
        const float* c0p = coords + (size_t)(gt0 + t) * 3;
        const float d0 = cj[0]-c0p[0], d1 = cj[1]-c0p[1], d2 = cj[2]-c0p[2];
        const float dn = sqrtf(d0*d0 + d1*d1 + d2*d2);
        const float inv = dn > 1e-6f ? 1.f/dn : 0.f;
        rhp[(t*3+k)*4+0] = d0*inv; rhp[(t*3+k)*4+1] = d1*inv; rhp[(t*3+k)*4+2] = d2*inv;
    }
    __syncthreads();

    const f32x4 fz = {0.f,0.f,0.f,0.f};
    f32x4 acc_s[2][2] = {{fz,fz},{fz,fz}};   // [m][u]
    f32x4 accv[6] = {fz,fz,fz,fz,fz,fz};     // mi = d*2 + m
    f32x4 agc[2] = {fz, fz};                 // g accumulator, per-k

    const int bt = tid >> 4;   // token 0..31
    const int bx = tid & 15;

#pragma unroll
    for (int k = 0; k < 3; ++k) {
        const int jn = n0 + bt + k - 1;
        const bool valid = (unsigned)jn < (unsigned)N_;
        const size_t j = (size_t)seq0 + (valid ? jn : 0);
        // ---- s_win: 16 channels/thread
        {
            const int c0 = bx * 16;
            float v[16];
            if (valid) {
                const float4* sp = (const float4*)(x_s + j*256 + c0);
#pragma unroll
                for (int i = 0; i < 4; ++i) {
                    float4 f = sp[i];
                    v[4*i]=f.x; v[4*i+1]=f.y; v[4*i+2]=f.z; v[4*i+3]=f.w;
                }
            } else {
#pragma unroll
                for (int i = 0; i < 16; ++i) v[i] = 0.f;
            }
            short8 p0, p1;
#pragma unroll
            for (int i = 0; i < 8; ++i) { p0[i]=(short)f2b(v[i]); p1[i]=(short)f2b(v[8+i]); }
            *(short8*)(fs + bt*392 + c0)     = p0;
            *(short8*)(fs + bt*392 + c0 + 8) = p1;
        }
        // ---- x_v-derived: vdot / vwin / cross, 8 channels/thread in 2 halves
        {
            const int c0 = bx * 8;
            const float r0 = rhp[(bt*3+k)*4+0];
            const float r1 = rhp[(bt*3+k)*4+1];
            const float r2 = rhp[(bt*3+k)*4+2];
#pragma unroll
            for (int hh = 0; hh < 2; ++hh) {
                float vv[12];
                if (valid) {
                    const float4* vp = (const float4*)(x_v + ((size_t)j*128 + c0 + 4*hh)*3);
#pragma unroll
                    for (int i = 0; i < 3; ++i) {
                        float4 f = vp[i];
                        vv[4*i]=f.x; vv[4*i+1]=f.y; vv[4*i+2]=f.z; vv[4*i+3]=f.w;
                    }
                } else {
#pragma unroll
                    for (int i = 0; i < 12; ++i) vv[i] = 0.f;
                }
                short4v dv, w0, w1, w2, x0, x1, x2;
#pragma unroll
                for (int m = 0; m < 4; ++m) {
                    const float a0 = vv[3*m], a1 = vv[3*m+1], a2 = vv[3*m+2];
                    dv[m] = (short)f2b(a0*r0 + a1*r1 + a2*r2);
                    w0[m] = (short)f2b(a0); w1[m] = (short)f2b(a1); w2[m] = (short)f2b(a2);
                    x0[m] = (short)f2b(a1*r2 - a2*r1);
                    x1[m] = (short)f2b(a2*r0 - a0*r2);
                    x2[m] = (short)f2b(a0*r1 - a1*r0);
                }
                const int cc = c0 + 4*hh;
                *(short4v*)(fs + bt*392 + 256 + cc)          = dv;
                *(short4v*)(fv + (0*32+bt)*264 + cc)         = w0;
                *(short4v*)(fv + (1*32+bt)*264 + cc)         = w1;
                *(short4v*)(fv + (2*32+bt)*264 + cc)         = w2;
                *(short4v*)(fv + (0*32+bt)*264 + 128 + cc)   = x0;
                *(short4v*)(fv + (1*32+bt)*264 + 128 + cc)   = x1;
                *(short4v*)(fv + (2*32+bt)*264 + 128 + cc)   = x2;
            }
        }
        __syncthreads();

        // ---- scalar conv GEMM (K=384) + g GEMM (K=256, shares a-frags)
        {
            const u16* bS0 = wt + OFF_CS + k*384 + (size_t)((2*w+0)*16+lm)*1152;
            const u16* bS1 = wt + OFF_CS + k*384 + (size_t)((2*w+1)*16+lm)*1152;
            const u16* bGp = wt + OFF_G  + k*256 + (size_t)(w*16+lm)*768;
            short8 b0 = *(const short8*)(bS0 + lk8);
            short8 b1 = *(const short8*)(bS1 + lk8);
            short8 bg = *(const short8*)(bGp + lk8);
#pragma unroll
            for (int ks = 0; ks < 12; ++ks) {
                const int ko = ks*32 + lk8;
                const int nk = (ks < 11 ? ks+1 : ks)*32 + lk8;
                short8 nb0 = *(const short8*)(bS0 + nk);
                short8 nb1 = *(const short8*)(bS1 + nk);
                const short8 a0 = *(const short8*)(fs + lm*392 + ko);
                const short8 a1 = *(const short8*)(fs + (16+lm)*392 + ko);
                acc_s[0][0] = MFMA(a0, b0, acc_s[0][0]);
                acc_s[1][0] = MFMA(a1, b0, acc_s[1][0]);
                acc_s[0][1] = MFMA(a0, b1, acc_s[0][1]);
                acc_s[1][1] = MFMA(a1, b1, acc_s[1][1]);
                if (ks < 8) {
                    agc[0] = MFMA(a0, bg, agc[0]);
                    agc[1] = MFMA(a1, bg, agc[1]);
                    const int gk = (ks < 7 ? ks+1 : ks)*32 + lk8;
                    bg = *(const short8*)(bGp + gk);
                }
                b0 = nb0; b1 = nb1;
            }
        }
        // ---- vec conv GEMM: [96 x 256] x [256 x 128]
        {
            const u16* bVp = wt + OFF_V + k*256 + (size_t)(w*16+lm)*768;
            short8 bv = *(const short8*)(bVp + lk8);
#pragma unroll
            for (int ks = 0; ks < 8; ++ks) {
                const int ko = ks*32 + lk8;
                const int nk = (ks < 7 ? ks+1 : ks)*32 + lk8;
                short8 nbv = *(const short8*)(bVp + nk);
#pragma unroll
                for (int mi = 0; mi < 6; ++mi) {
                    const short8 a = *(const short8*)(fv + (mi*16+lm)*264 + ko);
                    accv[mi] = MFMA(a, bv, accv[mi]);
                }
                bv = nbv;
            }
        }
        // ---- fold g into accv for this k (token t = (mi&1)*16+lq4+q, d = mi>>1)
#pragma unroll
        for (int mi = 0; mi < 6; ++mi) {
            const int m = mi & 1, d = mi >> 1;
#pragma unroll
            for (int q = 0; q < 4; ++q)
                accv[mi][q] += agc[m][q] * rhp[((m*16+lq4+q)*3 + k)*4 + d];
        }
        agc[0] = fz; agc[1] = fz;
        __syncthreads();
    }

    // ---- scales
    const float inv_fs = 0.029462783f;     // 1/sqrt(1152)
    const float inv_fv = 0.0255155136f;    // 1/sqrt(1536)
#pragma unroll
    for (int m = 0; m < 2; ++m)
#pragma unroll
        for (int u = 0; u < 2; ++u)
#pragma unroll
            for (int q = 0; q < 4; ++q) acc_s[m][u][q] *= inv_fs;
#pragma unroll
    for (int mi = 0; mi < 6; ++mi)
#pragma unroll
        for (int q = 0; q < 4; ++q) accv[mi][q] *= inv_fv;

    // ---- LN1
    float p1[2][4], p2[2][4], pv[2][4], mu[2][4], ss[2][4], vs[2][4];
#pragma unroll
    for (int m = 0; m < 2; ++m)
#pragma unroll
        for (int q = 0; q < 4; ++q) {
            float a = 0.f, b = 0.f, c = 0.f;
#pragma unroll
            for (int u = 0; u < 2; ++u) { const float x = acc_s[m][u][q]; a += x; b += x*x; }
#pragma unroll
            for (int d = 0; d < 3; ++d) { const float x = accv[d*2+m][q]; c += x*x; }
            p1[m][q] = a; p2[m][q] = b; pv[m][q] = c;
        }
    ln_reduce8(p1, p2, pv, red, lm, lq4, w, mu, ss, vs);

    // apply LN1 + bf16 staging for SI
#pragma unroll
    for (int m = 0; m < 2; ++m)
#pragma unroll
        for (int u = 0; u < 2; ++u)
#pragma unroll
            for (int q = 0; q < 4; ++q) {
                const float h = (acc_s[m][u][q] - mu[m][q]) * ss[m][q];
                acc_s[m][u][q] = h;
                hsb[(m*16+lq4+q)*264 + (2*w+u)*16 + lm] = f2b(h);
            }
#pragma unroll
    for (int mi = 0; mi < 6; ++mi)
#pragma unroll
        for (int q = 0; q < 4; ++q) {
            const float h = accv[mi][q] * vs[mi&1][q];
            accv[mi][q] = h;
            hvb[(mi*16+lq4+q)*136 + w*16 + lm] = f2b(h);
        }
    __syncthreads();

    // ---- SI GEMMs
    f32x4 accs[2][2] = {{fz,fz},{fz,fz}};
    f32x4 accw[6] = {fz,fz,fz,fz,fz,fz};
    {
        const u16* bP0 = wt + OFF_SS + (size_t)((2*w+0)*16+lm)*256;
        const u16* bP1 = wt + OFF_SS + (size_t)((2*w+1)*16+lm)*256;
        short8 c0 = *(const short8*)(bP0 + lk8);
        short8 c1 = *(const short8*)(bP1 + lk8);
#pragma unroll
        for (int ks = 0; ks < 8; ++ks) {
            const int ko = ks*32 + lk8;
            const int nk = (ks < 7 ? ks+1 : ks)*32 + lk8;
            short8 nc0 = *(const short8*)(bP0 + nk);
            short8 nc1 = *(const short8*)(bP1 + nk);
            const short8 a0 = *(const short8*)(hsb + lm*264 + ko);
            const short8 a1 = *(const short8*)(hsb + (16+lm)*264 + ko);
            accs[0][0] = MFMA(a0, c0, accs[0][0]);
            accs[1][0] = MFMA(a1, c0, accs[1][0]);
            accs[0][1] = MFMA(a0, c1, accs[0][1]);
            accs[1][1] = MFMA(a1, c1, accs[1][1]);
            c0 = nc0; c1 = nc1;
        }
        const u16* bPv = wt + OFF_SV + (size_t)(w*16+lm)*128;
        short8 cv = *(const short8*)(bPv + lk8);
#pragma unroll
        for (int ks = 0; ks < 4; ++ks) {
            const int ko = ks*32 + lk8;
            const int nk = (ks < 3 ? ks+1 : ks)*32 + lk8;
            short8 ncv = *(const short8*)(bPv + nk);
#pragma unroll
            for (int mi = 0; mi < 6; ++mi) {
                const short8 a = *(const short8*)(hvb + (mi*16+lm)*136 + ko);
                accw[mi] = MFMA(a, cv, accw[mi]);
            }
            cv = ncv;
        }
    }

    // ---- y = h + SI
#pragma unroll
    for (int m = 0; m < 2; ++m)
#pragma unroll
        for (int u = 0; u < 2; ++u)
#pragma unroll
            for (int q = 0; q < 4; ++q) acc_s[m][u][q] += accs[m][u][q] * 0.0625f;
#pragma unroll
    for (int mi = 0; mi < 6; ++mi)
#pragma unroll
        for (int q = 0; q < 4; ++q) accv[mi][q] += accw[mi][q] * 0.08838834764f;

    // ---- LN2 partials; x_v residual loads issued early (hide under reduce)
#pragma unroll
    for (int m = 0; m < 2; ++m)
#pragma unroll
        for (int q = 0; q < 4; ++q) {
            float a = 0.f, b = 0.f, c = 0.f;
#pragma unroll
            for (int u = 0; u < 2; ++u) { const float x = acc_s[m][u][q]; a += x; b += x*x; }
#pragma unroll
            for (int d = 0; d < 3; ++d) { const float x = accv[d*2+m][q]; c += x*x; }
            p1[m][q] = a; p2[m][q] = b; pv[m][q] = c;
        }
    float4 xr[6];
    {
        const float4* xvsrc = (const float4*)(x_v + (size_t)gt0 * 384);
#pragma unroll
        for (int i = 0; i < 6; ++i) xr[i] = xvsrc[tid + i*512];
    }
    ln_reduce8(p1, p2, pv, red, lm, lq4, w, mu, ss, vs);   // 1st barrier also fences hvb reads
#pragma unroll
    for (int i = 0; i < 6; ++i) ((float4*)xvL)[tid + i*512] = xr[i];
    __syncthreads();

    // ---- apply LN2 + residuals
#pragma unroll
    for (int m = 0; m < 2; ++m)
#pragma unroll
        for (int u = 0; u < 2; ++u)
#pragma unroll
            for (int q = 0; q < 4; ++q)
                acc_s[m][u][q] = (acc_s[m][u][q] - mu[m][q]) * ss[m][q]
                    + x_s[(size_t)(gt0 + m*16 + lq4 + q)*256 + (2*w+u)*16 + lm];
#pragma unroll
    for (int mi = 0; mi < 6; ++mi)
#pragma unroll
        for (int q = 0; q < 4; ++q) {
            const int t = (mi&1)*16 + lq4 + q;
            accv[mi][q] = accv[mi][q] * vs[mi&1][q]
                + xvL[t*384 + (w*16+lm)*3 + (mi>>1)];
        }

    // ---- LN3
#pragma unroll
    for (int m = 0; m < 2; ++m)
#pragma unroll
        for (int q = 0; q < 4; ++q) {
            float a = 0.f, b = 0.f, c = 0.f;
#pragma unroll
            for (int u = 0; u < 2; ++u) { const float x = acc_s[m][u][q]; a += x; b += x*x; }
#pragma unroll
            for (int d = 0; d < 3; ++d) { const float x = accv[d*2+m][q]; c += x*x; }
            p1[m][q] = a; p2[m][q] = b; pv[m][q] = c;
        }
    ln_reduce8(p1, p2, pv, red, lm, lq4, w, mu, ss, vs);

    // z_s: direct store (coalesced per 16-lane group)
#pragma unroll
    for (int m = 0; m < 2; ++m)
#pragma unroll
        for (int u = 0; u < 2; ++u)
#pragma unroll
            for (int q = 0; q < 4; ++q)
                out[(size_t)(gt0 + m*16 + lq4 + q)*256 + (2*w+u)*16 + lm] =
                    (acc_s[m][u][q] - mu[m][q]) * ss[m][q];
    // z_v: stage in LDS, then coalesced float4 copy
#pragma unroll
    for (int mi = 0; mi < 6; ++mi)
#pragma unroll
        for (int q = 0; q < 4; ++q) {
            const int t = (mi&1)*16 + lq4 + q;
            xvL[t*384 + (w*16+lm)*3 + (mi>>1)] = accv[mi][q] * vs[mi&1][q];
        }
    __syncthreads();
    {
        float4* dst = (float4*)(out + ZV0 + (size_t)gt0 * 384);
#pragma unroll
        for (int i = 0; i < 6; ++i) dst[tid + i*512] = ((const float4*)xvL)[tid + i*512];
    }
}

extern "C" void kernel_launch(void* const* d_in, const int* in_sizes, int n_in,
                              void* d_out, int out_size, void* d_ws, size_t ws_size,
                              hipStream_t stream) {
    const float* x_s    = (const float*)d_in[0];
    const float* x_v    = (const float*)d_in[1];
    const float* coords = (const float*)d_in[2];
    const float* Wcs    = (const float*)d_in[3];
    const float* Wcv    = (const float*)d_in[4];
    const float* Wss    = (const float*)d_in[5];
    const float* Wsv    = (const float*)d_in[6];
    float* out = (float*)d_out;
    u16* ws = (u16*)d_ws;

    hipLaunchKernelGGL(prep_weights, dim3(560), dim3(256), 0, stream,
                       Wcs, Wcv, Wss, Wsv, ws);
    hipLaunchKernelGGL(mixing_main, dim3((B_ * N_) / TB), dim3(512), 0, stream,
                       x_s, x_v, coords, ws, out);
}